// Round 5
// baseline (987.403 us; speedup 1.0000x reference)
//
#include <hip/hip_runtime.h>

// Problem constants (fixed by the reference).
#define N_FEAT  200000
#define DIM     512
#define KPROTO  64
#define CH      16                 // rows per fused iteration
#define NITER   (N_FEAT / CH)      // 12500, exact
#define APITCH  520                // f16 elems per LDS row (1040 B)
#define SPITCH  65                 // sims pitch (dwords)

typedef _Float16 f16;
typedef _Float16 f16x8 __attribute__((ext_vector_type(8)));
typedef _Float16 f16x4 __attribute__((ext_vector_type(4)));
typedef float    f32x4 __attribute__((ext_vector_type(4)));

// ws layout (bytes):
//   [0,     65536) : p_h    f16 [64][512]    normalized prototypes
//   [65536, 65792) : counts int [64]
//   [66560, ...)   : part   f32 [nblk][64*512] per-block partial sums
#define WS_PH     0
#define WS_COUNTS 65536
#define WS_PART   66560

// ---------------------------------------------------------------- proto prep
__global__ __launch_bounds__(256) void proto_prep(const float* __restrict__ P,
                                                  f16* __restrict__ Ph) {
    __shared__ float red[4];
    __shared__ float s_scale;
    int k = blockIdx.x;
    int t = threadIdx.x;
    const float* row = P + k * DIM;
    float a = row[t], b = row[t + 256];
    float ss = a * a + b * b;
    #pragma unroll
    for (int off = 32; off; off >>= 1) ss += __shfl_down(ss, off);
    int lane = t & 63, wid = t >> 6;
    if (lane == 0) red[wid] = ss;
    __syncthreads();
    if (t == 0) {
        float tot = red[0] + red[1] + red[2] + red[3];
        s_scale = 1.0f / fmaxf(sqrtf(tot), 1e-8f);
    }
    __syncthreads();
    float sc = s_scale;
    Ph[k * DIM + t]       = (f16)(a * sc);
    Ph[k * DIM + t + 256] = (f16)(b * sc);
}

// ---------------------------------------------------------------- fused pass
// One kernel reads F exactly once. Per 16-row iteration (3 barriers):
//   stage f16 (from regs) -> MFMA sims -> argmax -> ds_add accumulate (regs).
// acc[64][512] f32 in LDS (128 KB); accumulation is fire-and-forget
// ds_add_f32 from the f32 prefetch registers (no RMW chain, no Al re-read,
// full f32 precision). LDS = 152.2 KB -> 1 block/CU, 4 waves.
__global__ __launch_bounds__(256) void fused_k(const float* __restrict__ F,
                                               const f16* __restrict__ Ph,
                                               int* __restrict__ counts,
                                               float* __restrict__ part) {
    __shared__ float acc[KPROTO * DIM];     // 131072 B
    __shared__ f16   Al[CH * APITCH];       //  16640 B
    __shared__ float sims[CH * SPITCH];     //   4160 B
    __shared__ int   sasg[CH];
    __shared__ int   hist[KPROTO];

    int t    = threadIdx.x;
    int lane = t & 63;
    int wid  = t >> 6;       // wave id = 16-proto tile
    int cq   = lane >> 4;    // quad
    int cl   = lane & 15;

    #pragma unroll
    for (int m = 0; m < 128; ++m) acc[t + m * 256] = 0.0f;
    if (t < KPROTO) hist[t] = 0;

    // B fragments resident in registers: B[n = wid*16+cl][k = cq*8 + ks*32 + j]
    f16x8 bfrag[16];
    {
        const f16* pb = Ph + (wid * 16 + cl) * DIM + cq * 8;
        #pragma unroll
        for (int ks = 0; ks < 16; ++ks)
            bfrag[ks] = *(const f16x8*)(pb + ks * 32);
    }

    int r   = t >> 4;        // staged row 0..15 (16 threads/row)
    int c16 = t & 15;        // float4 column group
    const float* srcbase = F + (size_t)r * DIM + c16 * 4;

    f32x4 vA[8], vB[8];      // double-buffered prefetch registers
    const int GS = gridDim.x;
    int it0 = blockIdx.x;
    {
        const float* s = srcbase + (size_t)it0 * (CH * DIM);
        #pragma unroll
        for (int j = 0; j < 8; ++j) vA[j] = *(const f32x4*)(s + j * 64);
    }
    __syncthreads();         // acc/hist zero visible

// One fused iteration. VC = current rows (registers), VN = prefetch target.
// 3 barriers; accumulate reads only registers + sasg, so no bottom barrier:
// the next stage writes Al, which accumulate never touches.
#define BODY(IT, VC, VN)                                                      \
    {                                                                         \
        { /* stage current rows as f16 */                                     \
            f16* dst = Al + r * APITCH + c16 * 4;                             \
            _Pragma("unroll")                                                 \
            for (int j = 0; j < 8; ++j) {                                     \
                f16x4 h;                                                      \
                h.x = (f16)VC[j].x; h.y = (f16)VC[j].y;                       \
                h.z = (f16)VC[j].z; h.w = (f16)VC[j].w;                       \
                *(f16x4*)(dst + j * 64) = h;                                  \
            }                                                                 \
        }                                                                     \
        { /* issue next iteration's loads (land during compute) */            \
            int nx = (IT) + GS;                                               \
            if (nx < NITER) {                                                 \
                const float* s2 = srcbase + (size_t)nx * (CH * DIM);          \
                _Pragma("unroll")                                             \
                for (int j = 0; j < 8; ++j) VN[j] = *(const f32x4*)(s2 + j * 64); \
            }                                                                 \
        }                                                                     \
        __syncthreads();     /* Al ready */                                   \
        { /* MFMA: 16 rows x wave's 16 protos, K=512 */                       \
            f32x4 a2 = {0.f, 0.f, 0.f, 0.f};                                  \
            const f16* arow = Al + cl * APITCH + cq * 8;                      \
            _Pragma("unroll")                                                 \
            for (int ks = 0; ks < 16; ++ks) {                                 \
                f16x8 a = *(const f16x8*)(arow + ks * 32);                    \
                a2 = __builtin_amdgcn_mfma_f32_16x16x32_f16(a, bfrag[ks], a2, 0, 0, 0); \
            }                                                                 \
            _Pragma("unroll")                                                 \
            for (int q = 0; q < 4; ++q)                                       \
                sims[(cq * 4 + q) * SPITCH + wid * 16 + cl] = a2[q];          \
        }                                                                     \
        __syncthreads();     /* sims ready */                                 \
        /* argmax: 4 threads/row, 2 shfl combines (first-max = jnp.argmax) */ \
        if (t < 64) {                                                         \
            int row  = t >> 2;                                                \
            int quar = t & 3;                                                 \
            const float* srow = sims + row * SPITCH + quar * 16;              \
            float best = srow[0];                                             \
            int bi = 0;                                                       \
            _Pragma("unroll")                                                 \
            for (int j = 1; j < 16; ++j) {                                    \
                float x = srow[j];                                            \
                if (x > best) { best = x; bi = j; }                           \
            }                                                                 \
            bi += quar * 16;                                                  \
            float ob = __shfl_xor(best, 1); int oi = __shfl_xor(bi, 1);       \
            if (ob > best || (ob == best && oi < bi)) { best = ob; bi = oi; } \
            ob = __shfl_xor(best, 2); oi = __shfl_xor(bi, 2);                 \
            if (ob > best || (ob == best && oi < bi)) { best = ob; bi = oi; } \
            if (quar == 0) { sasg[row] = bi; atomicAdd(&hist[bi], 1); }       \
        }                                                                     \
        __syncthreads();     /* sasg ready */                                 \
        { /* accumulate from registers: fire-and-forget ds_add_f32 */         \
            int a = sasg[r];                                                  \
            float* pdst = acc + a * DIM + c16 * 4;                            \
            _Pragma("unroll")                                                 \
            for (int j = 0; j < 8; ++j) {                                     \
                atomicAdd(pdst + j * 64 + 0, VC[j].x);                        \
                atomicAdd(pdst + j * 64 + 1, VC[j].y);                        \
                atomicAdd(pdst + j * 64 + 2, VC[j].z);                        \
                atomicAdd(pdst + j * 64 + 3, VC[j].w);                        \
            }                                                                 \
        }                                                                     \
    }

    for (int it = it0; it < NITER; it += 2 * GS) {
        BODY(it, vA, vB);
        if (it + GS < NITER)     // block-uniform: barriers inside are safe
            BODY(it + GS, vB, vA);
    }
#undef BODY

    __syncthreads();         // all ds_adds complete (lgkmcnt drained per wave)

    // ---- flush per-block partial (plain coalesced stores) + counts
    {
        f32x4* d4 = (f32x4*)(part + (size_t)blockIdx.x * (KPROTO * DIM));
        const f32x4* a4 = (const f32x4*)acc;
        #pragma unroll
        for (int m = 0; m < 32; ++m) d4[t + m * 256] = a4[t + m * 256];
    }
    if (t < KPROTO) atomicAdd(&counts[t], hist[t]);
}

// ---------------------------------------------------------------- EMA epilogue
// Reduce npart per-block partials per element, then EMA.
__global__ __launch_bounds__(256) void ema_k(const float* __restrict__ P,
                                             const float* __restrict__ part,
                                             const int* __restrict__ counts,
                                             float* __restrict__ out,
                                             int npart) {
    int idx = blockIdx.x * 256 + threadIdx.x;   // 0..32767
    int k = idx >> 9;
    float p = P[idx];
    int c = counts[k];
    const float* q = part + idx;
    float a0 = 0.f, a1 = 0.f, a2 = 0.f, a3 = 0.f;
    for (int g = 0; g < npart; g += 4) {        // npart multiple of 4
        a0 += q[(size_t)(g + 0) * (KPROTO * DIM)];
        a1 += q[(size_t)(g + 1) * (KPROTO * DIM)];
        a2 += q[(size_t)(g + 2) * (KPROTO * DIM)];
        a3 += q[(size_t)(g + 3) * (KPROTO * DIM)];
    }
    float s = (a0 + a1) + (a2 + a3);
    float o = p;
    if (c > 0) o = 0.9f * p + 0.1f * (s / (float)c);
    out[idx] = o;
}

// ---------------------------------------------------------------- launch
extern "C" void kernel_launch(void* const* d_in, const int* in_sizes, int n_in,
                              void* d_out, int out_size, void* d_ws, size_t ws_size,
                              hipStream_t stream) {
    const float* F = (const float*)d_in[0];   // [200000][512]
    const float* P = (const float*)d_in[1];   // [64][512]
    char* ws = (char*)d_ws;
    f16*   Ph     = (f16*)(ws + WS_PH);
    int*   counts = (int*)(ws + WS_COUNTS);
    float* part   = (float*)(ws + WS_PART);
    float* out    = (float*)d_out;

    // Partial-buffer grid sized to workspace (256 known to fit).
    int nblk = 256;
    while (nblk > 32 &&
           ws_size < (size_t)WS_PART + (size_t)nblk * KPROTO * DIM * sizeof(float))
        nblk >>= 1;

    hipMemsetAsync(counts, 0, KPROTO * sizeof(int), stream);

    proto_prep<<<KPROTO, 256, 0, stream>>>(P, Ph);
    fused_k<<<nblk, 256, 0, stream>>>(F, Ph, counts, part);
    ema_k<<<(KPROTO * DIM) / 256, 256, 0, stream>>>(P, part, counts, out, nblk);
}